// Round 1
// 631.693 us; speedup vs baseline: 1.0317x; 1.0317x over previous
//
#include <hip/hip_runtime.h>

typedef unsigned short u16;
typedef unsigned int   u32;
typedef __bf16 bf16x8 __attribute__((ext_vector_type(8)));
typedef float  f32x4  __attribute__((ext_vector_type(4)));

#define DEVI __device__ __forceinline__

// B=8, S=N=1024, IMG_DIM=1024, TXT_DIM=768, INNER=1024, N_HEADS=16, HEAD_DIM=64, P=3
// Inputs: FLOAT32 (reference dtype). Outputs: FLOAT32 (reference dtype).
// out layout: Q | K | V | Q' | K', each [B,16,L,64] flat = 8*16*1024*64 elements

DEVI u16 f2bf(float f) {
    u32 u = __float_as_uint(f);
    return (u16)((u + 0x7fffu + ((u >> 16) & 1u)) >> 16);   // RNE fp32->bf16
}
DEVI u32 pk2(float lo, float hi) { return (u32)f2bf(lo) | ((u32)f2bf(hi) << 16); }

// ---------------------------------------------------------------------------
// Routing: ONE WAVE PER TOKEN (was: one thread per token -> 1.4% occupancy,
// 115 us latency-bound). Each lane reads a coalesced float4 slice of the row
// (D % 256 == 0 so no bounds checks), butterfly-reduce the 3 dot products
// across 64 lanes, lane 0 does the strict-> first-argmax (np.argmax
// semantics) and the atomic compaction. 8192 waves = 2048 blocks of 256.
// ---------------------------------------------------------------------------
__global__ __launch_bounds__(256)
void route_kernel(const float* __restrict__ X, const float* __restrict__ Wr,
                  int D, int ntok, int* __restrict__ cnt, int* __restrict__ list)
{
    const int wave = (blockIdx.x * blockDim.x + threadIdx.x) >> 6;
    const int lane = threadIdx.x & 63;
    if (wave >= ntok) return;

    const float* x  = X + (size_t)wave * D;
    const float* w0 = Wr;
    const float* w1 = Wr + D;
    const float* w2 = Wr + 2 * D;

    float a0 = 0.f, a1 = 0.f, a2 = 0.f;
    // D = 1024 -> 4 iterations; D = 768 -> 3 iterations. Fully coalesced:
    // lane l reads bytes [16*l, 16*l+16) of each 1 KiB segment.
    for (int d = lane * 4; d < D; d += 256) {
        float4 xv = *(const float4*)(x + d);
        float4 v0 = *(const float4*)(w0 + d);
        float4 v1 = *(const float4*)(w1 + d);
        float4 v2 = *(const float4*)(w2 + d);
        a0 += xv.x * v0.x + xv.y * v0.y + xv.z * v0.z + xv.w * v0.w;
        a1 += xv.x * v1.x + xv.y * v1.y + xv.z * v1.z + xv.w * v1.w;
        a2 += xv.x * v2.x + xv.y * v2.y + xv.z * v2.z + xv.w * v2.w;
    }

    // 64-lane butterfly reduction (wave = 64 on gfx950)
#pragma unroll
    for (int m = 32; m; m >>= 1) {
        a0 += __shfl_xor(a0, m);
        a1 += __shfl_xor(a1, m);
        a2 += __shfl_xor(a2, m);
    }

    if (lane == 0) {
        int s = 0; float best = a0;
        if (a1 > best) { best = a1; s = 1; }
        if (a2 > best) { best = a2; s = 2; }
        int slot = atomicAdd(&cnt[s], 1);
        list[s * 8192 + slot] = wave;
    }
}

// ---------------------------------------------------------------------------
// GEMM core: 128x128 tile, BK=32, 4 waves in 2x2, each wave 4x4 MFMA tiles of
// 16x16x32 bf16 (fp32 accumulate). Inputs are fp32 in global memory; staging
// converts fp32 -> bf16 (RNE) on the fly via VGPR round-trip.
// Thread tid stages 8-elem chunks c=tid and c=tid+256 of each 128x32 tile:
// chunk c -> LDS u16 offset 8*c (row c>>2, k-off (c&3)*8). Every LDS byte is
// written before any read; barriers on both sides.
// ---------------------------------------------------------------------------
template <int KD>
DEVI void gemm_core(const float* gA1, const float* gA2, const float* gB1, const float* gB2,
                    u16* As, u16* Bs, int tid, int wv, int lane, f32x4 (&acc)[4][4])
{
    uint4* sA1 = (uint4*)(As + 8 * tid);
    uint4* sA2 = (uint4*)(As + 8 * (tid + 256));
    uint4* sB1 = (uint4*)(Bs + 8 * tid);
    uint4* sB2 = (uint4*)(Bs + 8 * (tid + 256));
    const int row15 = lane & 15;
    const int quad  = lane >> 4;
    const int wm = (wv & 1) * 64;
    const int wn = (wv >> 1) * 64;

    for (int k0 = 0; k0 < KD; k0 += 32) {
        float4 a1l = *(const float4*)(gA1 + k0);
        float4 a1h = *(const float4*)(gA1 + k0 + 4);
        float4 a2l = *(const float4*)(gA2 + k0);
        float4 a2h = *(const float4*)(gA2 + k0 + 4);
        float4 b1l = *(const float4*)(gB1 + k0);
        float4 b1h = *(const float4*)(gB1 + k0 + 4);
        float4 b2l = *(const float4*)(gB2 + k0);
        float4 b2h = *(const float4*)(gB2 + k0 + 4);
        uint4 pa1 = { pk2(a1l.x, a1l.y), pk2(a1l.z, a1l.w), pk2(a1h.x, a1h.y), pk2(a1h.z, a1h.w) };
        uint4 pa2 = { pk2(a2l.x, a2l.y), pk2(a2l.z, a2l.w), pk2(a2h.x, a2h.y), pk2(a2h.z, a2h.w) };
        uint4 pb1 = { pk2(b1l.x, b1l.y), pk2(b1l.z, b1l.w), pk2(b1h.x, b1h.y), pk2(b1h.z, b1h.w) };
        uint4 pb2 = { pk2(b2l.x, b2l.y), pk2(b2l.z, b2l.w), pk2(b2h.x, b2h.y), pk2(b2h.z, b2h.w) };
        *sA1 = pa1;
        *sA2 = pa2;
        *sB1 = pb1;
        *sB2 = pb2;
        __syncthreads();

        bf16x8 a[4], b[4];
#pragma unroll
        for (int i = 0; i < 4; ++i)
            a[i] = *(const bf16x8*)(As + (wm + i * 16 + row15) * 32 + quad * 8);
#pragma unroll
        for (int j = 0; j < 4; ++j)
            b[j] = *(const bf16x8*)(Bs + (wn + j * 16 + row15) * 32 + quad * 8);
#pragma unroll
        for (int i = 0; i < 4; ++i)
#pragma unroll
            for (int j = 0; j < 4; ++j)
                acc[i][j] = __builtin_amdgcn_mfma_f32_16x16x32_bf16(a[i], b[j], acc[i][j], 0, 0, 0);
        __syncthreads();
    }
}

// ---------------------------------------------------------------------------
// Plain GEMM: C[m,n] = sum_k A[m,k] * W[n,k], written to head layout (fp32).
// m = b*1024 + l ; n = h*64 + d ; out[((b*16+h)*1024 + l)*64 + d]
// ---------------------------------------------------------------------------
template <int KD>
__global__ __launch_bounds__(256)
void gemm_heads(const float* __restrict__ A, const float* __restrict__ W, float* __restrict__ out)
{
    __shared__ __align__(16) u16 As[128 * 32];
    __shared__ __align__(16) u16 Bs[128 * 32];
    const int tid  = threadIdx.x;
    const int lane = tid & 63;
    const int wv   = tid >> 6;
    const int rowbase = blockIdx.x * 128;
    const int nbase   = blockIdx.y * 128;
    const int r1   = tid >> 2;
    const int koff = (tid & 3) * 8;

    const float* gA1 = A + (size_t)(rowbase + r1) * KD + koff;
    const float* gA2 = A + (size_t)(rowbase + 64 + r1) * KD + koff;
    const float* gB1 = W + (size_t)(nbase + r1) * KD + koff;
    const float* gB2 = W + (size_t)(nbase + 64 + r1) * KD + koff;

    f32x4 acc[4][4];
#pragma unroll
    for (int i = 0; i < 4; ++i)
#pragma unroll
        for (int j = 0; j < 4; ++j)
            acc[i][j] = (f32x4){0.f, 0.f, 0.f, 0.f};

    gemm_core<KD>(gA1, gA2, gB1, gB2, As, Bs, tid, wv, lane, acc);

    const int row15 = lane & 15, quad = lane >> 4;
    const int wm = (wv & 1) * 64, wn = (wv >> 1) * 64;
#pragma unroll
    for (int i = 0; i < 4; ++i) {
#pragma unroll
        for (int r = 0; r < 4; ++r) {
            int m = rowbase + wm + i * 16 + quad * 4 + r;
            int bb = m >> 10, l = m & 1023;
#pragma unroll
            for (int j = 0; j < 4; ++j) {
                int n = nbase + wn + j * 16 + row15;
                size_t off = (((size_t)(bb * 16 + (n >> 6)) * 1024) + l) * 64 + (n & 63);
                out[off] = acc[i][j][r];
            }
        }
    }
}

// ---------------------------------------------------------------------------
// Row-gathered GEMM over per-bank token lists (Q'/K'). grid.x = 66 row-tiles
// shared across 3 banks (sum ceil(cnt_p/128) <= 66); grid.y = 8 col-tiles.
// ---------------------------------------------------------------------------
template <int KD>
__global__ __launch_bounds__(256)
void gemm_prime(const float* __restrict__ A, const float* __restrict__ Wb,
                const int* __restrict__ cnt, const int* __restrict__ list,
                float* __restrict__ out)
{
    const int c0 = cnt[0], c1 = cnt[1], c2 = cnt[2];
    const int t0 = (c0 + 127) >> 7, t1 = (c1 + 127) >> 7, t2 = (c2 + 127) >> 7;
    const int rt = blockIdx.x;
    int bank, lt, cb;
    if (rt < t0)                { bank = 0; lt = rt;            cb = c0; }
    else if (rt < t0 + t1)      { bank = 1; lt = rt - t0;       cb = c1; }
    else if (rt < t0 + t1 + t2) { bank = 2; lt = rt - t0 - t1;  cb = c2; }
    else return;                       // uniform across block: no barrier reached

    const int* bl = list + bank * 8192;
    const float* W = Wb + (size_t)bank * 1024 * KD;

    __shared__ __align__(16) u16 As[128 * 32];
    __shared__ __align__(16) u16 Bs[128 * 32];
    const int tid  = threadIdx.x;
    const int lane = tid & 63;
    const int wv   = tid >> 6;
    const int nbase = blockIdx.y * 128;
    const int r1   = tid >> 2;
    const int koff = (tid & 3) * 8;

    int i1 = lt * 128 + r1;       if (i1 >= cb) i1 = cb - 1;
    int i2 = lt * 128 + 64 + r1;  if (i2 >= cb) i2 = cb - 1;
    const float* gA1 = A + (size_t)bl[i1] * KD + koff;
    const float* gA2 = A + (size_t)bl[i2] * KD + koff;
    const float* gB1 = W + (size_t)(nbase + r1) * KD + koff;
    const float* gB2 = W + (size_t)(nbase + 64 + r1) * KD + koff;

    f32x4 acc[4][4];
#pragma unroll
    for (int i = 0; i < 4; ++i)
#pragma unroll
        for (int j = 0; j < 4; ++j)
            acc[i][j] = (f32x4){0.f, 0.f, 0.f, 0.f};

    gemm_core<KD>(gA1, gA2, gB1, gB2, As, Bs, tid, wv, lane, acc);

    const int row15 = lane & 15, quad = lane >> 4;
    const int wm = (wv & 1) * 64, wn = (wv >> 1) * 64;
#pragma unroll
    for (int i = 0; i < 4; ++i) {
#pragma unroll
        for (int r = 0; r < 4; ++r) {
            int idx = lt * 128 + wm + i * 16 + quad * 4 + r;
            if (idx < cb) {
                int m = bl[idx];
                int bb = m >> 10, l = m & 1023;
#pragma unroll
                for (int j = 0; j < 4; ++j) {
                    int n = nbase + wn + j * 16 + row15;
                    size_t off = (((size_t)(bb * 16 + (n >> 6)) * 1024) + l) * 64 + (n & 63);
                    out[off] = acc[i][j][r];
                }
            }
        }
    }
}

// ---------------------------------------------------------------------------
extern "C" void kernel_launch(void* const* d_in, const int* in_sizes, int n_in,
                              void* d_out, int out_size, void* d_ws, size_t ws_size,
                              hipStream_t stream)
{
    const float* img = (const float*)d_in[0];
    const float* txt = (const float*)d_in[1];
    const float* Wq  = (const float*)d_in[2];
    const float* Wk  = (const float*)d_in[3];
    const float* Wv  = (const float*)d_in[4];
    const float* Wqb = (const float*)d_in[5];
    const float* Wkb = (const float*)d_in[6];
    const float* Wrq = (const float*)d_in[7];
    const float* Wrk = (const float*)d_in[8];
    float* out = (float*)d_out;

    int* cntq  = (int*)d_ws;                    // 3 ints
    int* cntk  = cntq + 3;                      // 3 ints
    int* qlist = (int*)((char*)d_ws + 32);      // 3*8192 ints
    int* klist = qlist + 3 * 8192;              // 3*8192 ints

    const size_t OSZ = (size_t)8 * 16 * 1024 * 64;   // 8,388,608 elements per output

    hipMemsetAsync(d_ws, 0, 32, stream);   // zero the 6 counters (ws is poisoned 0xAA)

    // one wave per token: 8192 tokens * 64 lanes = 524288 threads = 2048 blocks
    route_kernel<<<2048, 256, 0, stream>>>(img, Wrq, 1024, 8192, cntq, qlist);
    route_kernel<<<2048, 256, 0, stream>>>(txt, Wrk,  768, 8192, cntk, klist);

    gemm_heads<1024><<<dim3(64, 8), 256, 0, stream>>>(img, Wq, out);
    gemm_heads<768> <<<dim3(64, 8), 256, 0, stream>>>(txt, Wk, out + OSZ);
    gemm_heads<768> <<<dim3(64, 8), 256, 0, stream>>>(txt, Wv, out + 2 * OSZ);

    gemm_prime<1024><<<dim3(66, 8), 256, 0, stream>>>(img, Wqb, cntq, qlist, out + 3 * OSZ);
    gemm_prime<768> <<<dim3(66, 8), 256, 0, stream>>>(txt, Wkb, cntk, klist, out + 4 * OSZ);
}

// Round 2
// 459.857 us; speedup vs baseline: 1.4172x; 1.3737x over previous
//
#include <hip/hip_runtime.h>

typedef unsigned short u16;
typedef unsigned int   u32;
typedef __bf16 bf16x8 __attribute__((ext_vector_type(8)));
typedef float  f32x4  __attribute__((ext_vector_type(4)));

#define DEVI __device__ __forceinline__

// B=8, S=N=1024, IMG_DIM=1024, TXT_DIM=768, INNER=1024, N_HEADS=16, HEAD_DIM=64, P=3
// Inputs: FLOAT32 (reference dtype). Outputs: FLOAT32 (reference dtype).
// out layout: Q | K | V | Q' | K', each [B,16,L,64] flat = 8*16*1024*64 elements

DEVI u16 f2bf(float f) {
    u32 u = __float_as_uint(f);
    return (u16)((u + 0x7fffu + ((u >> 16) & 1u)) >> 16);   // RNE fp32->bf16
}
DEVI u32 pk2(float lo, float hi) { return (u32)f2bf(lo) | ((u32)f2bf(hi) << 16); }

// ---------------------------------------------------------------------------
// Routing v3. Round-1 evidence: 8192 device-scope atomicAdds to 3 counters in
// ONE cache line serialized at ~12.6 ns each = the whole 103 us (VALUBusy 2%,
// HBM 2%, occupancy 66% -- all pipes idle, waiting on the atomic chain).
// Fix: hierarchical compaction.
//   - block = 32 tokens (4 waves x 8 tokens; per-token numerics identical to
//     the passing kernel: lane-strided float4 loads + 64-lane butterfly).
//   - intra-block ranks via LDS atomics (3 addrs, <=32 ops).
//   - ONE global atomicAdd per bank per block; counters padded to separate
//     128-B cache lines (stride 32 ints) so the 3 chains don't collide.
//     768 global atomics total vs 8192, in 3 parallel chains of 256.
//   - q-route and k-route fused into one 512-block launch: both BW-bound,
//     share the device instead of paying two latency floors sequentially.
// ---------------------------------------------------------------------------
__global__ __launch_bounds__(256)
void route_fused(const float* __restrict__ img, const float* __restrict__ Wrq,
                 int* __restrict__ cntq, int* __restrict__ qlist,
                 const float* __restrict__ txt, const float* __restrict__ Wrk,
                 int* __restrict__ cntk, int* __restrict__ klist)
{
    const float* X; const float* Wr; int D; int* cnt; int* list; int tokbase;
    if (blockIdx.x < 256) { X = img; Wr = Wrq; D = 1024; cnt = cntq; list = qlist; tokbase = blockIdx.x * 32; }
    else                  { X = txt; Wr = Wrk; D = 768;  cnt = cntk; list = klist; tokbase = (blockIdx.x - 256) * 32; }

    __shared__ int lcnt[3];     // per-block per-bank token count
    __shared__ int base[3];     // global base slot per bank
    __shared__ u16 tbank[32];   // per local token: chosen bank
    __shared__ u16 trank[32];   // per local token: intra-block rank

    const int tid  = threadIdx.x;
    const int lane = tid & 63;
    const int wv   = tid >> 6;
    if (tid < 3) lcnt[tid] = 0;
    __syncthreads();

    const float* w0 = Wr;
    const float* w1 = Wr + D;
    const float* w2 = Wr + 2 * D;

    // each wave handles 8 consecutive tokens
    for (int t = 0; t < 8; ++t) {
        const int ltok = wv * 8 + t;
        const float* x = X + (size_t)(tokbase + ltok) * D;
        float a0 = 0.f, a1 = 0.f, a2 = 0.f;
        for (int d = lane * 4; d < D; d += 256) {
            float4 xv = *(const float4*)(x + d);
            float4 v0 = *(const float4*)(w0 + d);
            float4 v1 = *(const float4*)(w1 + d);
            float4 v2 = *(const float4*)(w2 + d);
            a0 += xv.x * v0.x + xv.y * v0.y + xv.z * v0.z + xv.w * v0.w;
            a1 += xv.x * v1.x + xv.y * v1.y + xv.z * v1.z + xv.w * v1.w;
            a2 += xv.x * v2.x + xv.y * v2.y + xv.z * v2.z + xv.w * v2.w;
        }
#pragma unroll
        for (int m = 32; m; m >>= 1) {
            a0 += __shfl_xor(a0, m);
            a1 += __shfl_xor(a1, m);
            a2 += __shfl_xor(a2, m);
        }
        if (lane == 0) {
            int s = 0; float best = a0;                       // strict >, first-max
            if (a1 > best) { best = a1; s = 1; }
            if (a2 > best) { best = a2; s = 2; }
            int r = atomicAdd(&lcnt[s], 1);                   // LDS atomic: cheap
            tbank[ltok] = (u16)s;
            trank[ltok] = (u16)r;
        }
    }
    __syncthreads();

    if (tid < 3) base[tid] = atomicAdd(&cnt[tid * 32], lcnt[tid]);   // padded lines
    __syncthreads();

    if (tid < 32) {
        int s = tbank[tid];
        list[s * 8192 + base[s] + trank[tid]] = tokbase + tid;
    }
}

// ---------------------------------------------------------------------------
// GEMM core: 128x128 tile, BK=32, 4 waves in 2x2, each wave 4x4 MFMA tiles of
// 16x16x32 bf16 (fp32 accumulate). Inputs are fp32 in global memory; staging
// converts fp32 -> bf16 (RNE) on the fly via VGPR round-trip.
// Thread tid stages 8-elem chunks c=tid and c=tid+256 of each 128x32 tile:
// chunk c -> LDS u16 offset 8*c (row c>>2, k-off (c&3)*8). Every LDS byte is
// written before any read; barriers on both sides.
// ---------------------------------------------------------------------------
template <int KD>
DEVI void gemm_core(const float* gA1, const float* gA2, const float* gB1, const float* gB2,
                    u16* As, u16* Bs, int tid, int wv, int lane, f32x4 (&acc)[4][4])
{
    uint4* sA1 = (uint4*)(As + 8 * tid);
    uint4* sA2 = (uint4*)(As + 8 * (tid + 256));
    uint4* sB1 = (uint4*)(Bs + 8 * tid);
    uint4* sB2 = (uint4*)(Bs + 8 * (tid + 256));
    const int row15 = lane & 15;
    const int quad  = lane >> 4;
    const int wm = (wv & 1) * 64;
    const int wn = (wv >> 1) * 64;

    for (int k0 = 0; k0 < KD; k0 += 32) {
        float4 a1l = *(const float4*)(gA1 + k0);
        float4 a1h = *(const float4*)(gA1 + k0 + 4);
        float4 a2l = *(const float4*)(gA2 + k0);
        float4 a2h = *(const float4*)(gA2 + k0 + 4);
        float4 b1l = *(const float4*)(gB1 + k0);
        float4 b1h = *(const float4*)(gB1 + k0 + 4);
        float4 b2l = *(const float4*)(gB2 + k0);
        float4 b2h = *(const float4*)(gB2 + k0 + 4);
        uint4 pa1 = { pk2(a1l.x, a1l.y), pk2(a1l.z, a1l.w), pk2(a1h.x, a1h.y), pk2(a1h.z, a1h.w) };
        uint4 pa2 = { pk2(a2l.x, a2l.y), pk2(a2l.z, a2l.w), pk2(a2h.x, a2h.y), pk2(a2h.z, a2h.w) };
        uint4 pb1 = { pk2(b1l.x, b1l.y), pk2(b1l.z, b1l.w), pk2(b1h.x, b1h.y), pk2(b1h.z, b1h.w) };
        uint4 pb2 = { pk2(b2l.x, b2l.y), pk2(b2l.z, b2l.w), pk2(b2h.x, b2h.y), pk2(b2h.z, b2h.w) };
        *sA1 = pa1;
        *sA2 = pa2;
        *sB1 = pb1;
        *sB2 = pb2;
        __syncthreads();

        bf16x8 a[4], b[4];
#pragma unroll
        for (int i = 0; i < 4; ++i)
            a[i] = *(const bf16x8*)(As + (wm + i * 16 + row15) * 32 + quad * 8);
#pragma unroll
        for (int j = 0; j < 4; ++j)
            b[j] = *(const bf16x8*)(Bs + (wn + j * 16 + row15) * 32 + quad * 8);
#pragma unroll
        for (int i = 0; i < 4; ++i)
#pragma unroll
            for (int j = 0; j < 4; ++j)
                acc[i][j] = __builtin_amdgcn_mfma_f32_16x16x32_bf16(a[i], b[j], acc[i][j], 0, 0, 0);
        __syncthreads();
    }
}

// ---------------------------------------------------------------------------
// Plain GEMM: C[m,n] = sum_k A[m,k] * W[n,k], written to head layout (fp32).
// m = b*1024 + l ; n = h*64 + d ; out[((b*16+h)*1024 + l)*64 + d]
// ---------------------------------------------------------------------------
template <int KD>
__global__ __launch_bounds__(256)
void gemm_heads(const float* __restrict__ A, const float* __restrict__ W, float* __restrict__ out)
{
    __shared__ __align__(16) u16 As[128 * 32];
    __shared__ __align__(16) u16 Bs[128 * 32];
    const int tid  = threadIdx.x;
    const int lane = tid & 63;
    const int wv   = tid >> 6;
    const int rowbase = blockIdx.x * 128;
    const int nbase   = blockIdx.y * 128;
    const int r1   = tid >> 2;
    const int koff = (tid & 3) * 8;

    const float* gA1 = A + (size_t)(rowbase + r1) * KD + koff;
    const float* gA2 = A + (size_t)(rowbase + 64 + r1) * KD + koff;
    const float* gB1 = W + (size_t)(nbase + r1) * KD + koff;
    const float* gB2 = W + (size_t)(nbase + 64 + r1) * KD + koff;

    f32x4 acc[4][4];
#pragma unroll
    for (int i = 0; i < 4; ++i)
#pragma unroll
        for (int j = 0; j < 4; ++j)
            acc[i][j] = (f32x4){0.f, 0.f, 0.f, 0.f};

    gemm_core<KD>(gA1, gA2, gB1, gB2, As, Bs, tid, wv, lane, acc);

    const int row15 = lane & 15, quad = lane >> 4;
    const int wm = (wv & 1) * 64, wn = (wv >> 1) * 64;
#pragma unroll
    for (int i = 0; i < 4; ++i) {
#pragma unroll
        for (int r = 0; r < 4; ++r) {
            int m = rowbase + wm + i * 16 + quad * 4 + r;
            int bb = m >> 10, l = m & 1023;
#pragma unroll
            for (int j = 0; j < 4; ++j) {
                int n = nbase + wn + j * 16 + row15;
                size_t off = (((size_t)(bb * 16 + (n >> 6)) * 1024) + l) * 64 + (n & 63);
                out[off] = acc[i][j][r];
            }
        }
    }
}

// ---------------------------------------------------------------------------
// Row-gathered GEMM over per-bank token lists (Q'/K'). grid.x = 66 row-tiles
// shared across 3 banks (sum ceil(cnt_p/128) <= 66); grid.y = 8 col-tiles.
// Counters are padded to 128-B lines: cnt[p*32].
// ---------------------------------------------------------------------------
template <int KD>
__global__ __launch_bounds__(256)
void gemm_prime(const float* __restrict__ A, const float* __restrict__ Wb,
                const int* __restrict__ cnt, const int* __restrict__ list,
                float* __restrict__ out)
{
    const int c0 = cnt[0], c1 = cnt[32], c2 = cnt[64];
    const int t0 = (c0 + 127) >> 7, t1 = (c1 + 127) >> 7, t2 = (c2 + 127) >> 7;
    const int rt = blockIdx.x;
    int bank, lt, cb;
    if (rt < t0)                { bank = 0; lt = rt;            cb = c0; }
    else if (rt < t0 + t1)      { bank = 1; lt = rt - t0;       cb = c1; }
    else if (rt < t0 + t1 + t2) { bank = 2; lt = rt - t0 - t1;  cb = c2; }
    else return;                       // uniform across block: no barrier reached

    const int* bl = list + bank * 8192;
    const float* W = Wb + (size_t)bank * 1024 * KD;

    __shared__ __align__(16) u16 As[128 * 32];
    __shared__ __align__(16) u16 Bs[128 * 32];
    const int tid  = threadIdx.x;
    const int lane = tid & 63;
    const int wv   = tid >> 6;
    const int nbase = blockIdx.y * 128;
    const int r1   = tid >> 2;
    const int koff = (tid & 3) * 8;

    int i1 = lt * 128 + r1;       if (i1 >= cb) i1 = cb - 1;
    int i2 = lt * 128 + 64 + r1;  if (i2 >= cb) i2 = cb - 1;
    const float* gA1 = A + (size_t)bl[i1] * KD + koff;
    const float* gA2 = A + (size_t)bl[i2] * KD + koff;
    const float* gB1 = W + (size_t)(nbase + r1) * KD + koff;
    const float* gB2 = W + (size_t)(nbase + 64 + r1) * KD + koff;

    f32x4 acc[4][4];
#pragma unroll
    for (int i = 0; i < 4; ++i)
#pragma unroll
        for (int j = 0; j < 4; ++j)
            acc[i][j] = (f32x4){0.f, 0.f, 0.f, 0.f};

    gemm_core<KD>(gA1, gA2, gB1, gB2, As, Bs, tid, wv, lane, acc);

    const int row15 = lane & 15, quad = lane >> 4;
    const int wm = (wv & 1) * 64, wn = (wv >> 1) * 64;
#pragma unroll
    for (int i = 0; i < 4; ++i) {
#pragma unroll
        for (int r = 0; r < 4; ++r) {
            int idx = lt * 128 + wm + i * 16 + quad * 4 + r;
            if (idx < cb) {
                int m = bl[idx];
                int bb = m >> 10, l = m & 1023;
#pragma unroll
                for (int j = 0; j < 4; ++j) {
                    int n = nbase + wn + j * 16 + row15;
                    size_t off = (((size_t)(bb * 16 + (n >> 6)) * 1024) + l) * 64 + (n & 63);
                    out[off] = acc[i][j][r];
                }
            }
        }
    }
}

// ---------------------------------------------------------------------------
extern "C" void kernel_launch(void* const* d_in, const int* in_sizes, int n_in,
                              void* d_out, int out_size, void* d_ws, size_t ws_size,
                              hipStream_t stream)
{
    const float* img = (const float*)d_in[0];
    const float* txt = (const float*)d_in[1];
    const float* Wq  = (const float*)d_in[2];
    const float* Wk  = (const float*)d_in[3];
    const float* Wv  = (const float*)d_in[4];
    const float* Wqb = (const float*)d_in[5];
    const float* Wkb = (const float*)d_in[6];
    const float* Wrq = (const float*)d_in[7];
    const float* Wrk = (const float*)d_in[8];
    float* out = (float*)d_out;

    // ws layout: padded counters (each on its own 128-B line), then lists.
    int* cntq  = (int*)d_ws;                    // ints [0],[32],[64]
    int* cntk  = (int*)d_ws + 128;              // ints [128],[160],[192] (abs)
    int* qlist = (int*)d_ws + 256;              // 3*8192 ints
    int* klist = qlist + 3 * 8192;              // 3*8192 ints

    const size_t OSZ = (size_t)8 * 16 * 1024 * 64;   // 8,388,608 elements per output

    hipMemsetAsync(d_ws, 0, 1024, stream);   // zero padded counters (ws poisoned 0xAA)

    // fused q+k routing: blocks [0,256) = img/1024, [256,512) = txt/768
    route_fused<<<512, 256, 0, stream>>>(img, Wrq, cntq, qlist, txt, Wrk, cntk, klist);

    gemm_heads<1024><<<dim3(64, 8), 256, 0, stream>>>(img, Wq, out);
    gemm_heads<768> <<<dim3(64, 8), 256, 0, stream>>>(txt, Wk, out + OSZ);
    gemm_heads<768> <<<dim3(64, 8), 256, 0, stream>>>(txt, Wv, out + 2 * OSZ);

    gemm_prime<1024><<<dim3(66, 8), 256, 0, stream>>>(img, Wqb, cntq, qlist, out + 3 * OSZ);
    gemm_prime<768> <<<dim3(66, 8), 256, 0, stream>>>(txt, Wkb, cntk, klist, out + 4 * OSZ);
}

// Round 3
// 413.970 us; speedup vs baseline: 1.5743x; 1.1108x over previous
//
#include <hip/hip_runtime.h>

typedef unsigned short u16;
typedef unsigned int   u32;
typedef __bf16 bf16x8 __attribute__((ext_vector_type(8)));
typedef float  f32x4  __attribute__((ext_vector_type(4)));

#define DEVI __device__ __forceinline__

// B=8, S=N=1024, IMG_DIM=1024, TXT_DIM=768, INNER=1024, N_HEADS=16, HEAD_DIM=64, P=3
// Inputs: FLOAT32 (reference dtype). Outputs: FLOAT32 (reference dtype).
// out layout: Q | K | V | Q' | K', each [B,16,L,64] flat = 8*16*1024*64 elements
//
// Round-3 structure:
//   route_fused : routing (hierarchical atomic compaction, proven r2) + fused
//                 fp32->bf16 conversion of img/txt into workspace.
//   cvt_weights : fp32->bf16 for the 5 weight tensors.
//   gemm_*      : bf16 inputs staged via global_load_lds width=16 (the m97
//                 ladder step: DMA direct to LDS, no VGPR round-trip, no cvt).
//                 Same 128x128 tile / BK=32 / 2x2 waves / 4x4 MFMA as before;
//                 conversion uses the same RNE f2bf -> outputs bit-identical.

DEVI u16 f2bf(float f) {
    u32 u = __float_as_uint(f);
    return (u16)((u + 0x7fffu + ((u >> 16) & 1u)) >> 16);   // RNE fp32->bf16
}
DEVI u32 pk2(float lo, float hi) { return (u32)f2bf(lo) | ((u32)f2bf(hi) << 16); }

DEVI void gload16(const u16* g, u16* s) {
    typedef __attribute__((address_space(1))) const unsigned int GU;
    typedef __attribute__((address_space(3))) unsigned int LU;
    __builtin_amdgcn_global_load_lds((GU*)g, (LU*)s, 16, 0, 0);  // 16B/lane DMA
}

// ---------------------------------------------------------------------------
// Routing + input conversion. 512 blocks x 512 threads; blocks [0,256) = img
// (D=1024), [256,512) = txt (D=768). 32 tokens/block, 8 waves x 4 tokens.
// Per token: lane-strided float4 loads (also stored as bf16 -> Xb), 64-lane
// butterfly reduce of 3 dots, strict-> first-argmax (np.argmax semantics).
// Compaction: LDS ranks, one global atomic per bank per block, counters on
// separate 128-B lines (3 parallel chains of 256 atomics -- proven r2 fix).
// ---------------------------------------------------------------------------
__global__ __launch_bounds__(512)
void route_fused(const float* __restrict__ img, const float* __restrict__ Wrq,
                 int* __restrict__ cntq, int* __restrict__ qlist, u16* __restrict__ imgB,
                 const float* __restrict__ txt, const float* __restrict__ Wrk,
                 int* __restrict__ cntk, int* __restrict__ klist, u16* __restrict__ txtB)
{
    const float* X; const float* Wr; int D; int* cnt; int* list; u16* Xb; int tokbase;
    if (blockIdx.x < 256) { X = img; Wr = Wrq; D = 1024; cnt = cntq; list = qlist; Xb = imgB; tokbase = blockIdx.x * 32; }
    else                  { X = txt; Wr = Wrk; D = 768;  cnt = cntk; list = klist; Xb = txtB; tokbase = (blockIdx.x - 256) * 32; }

    __shared__ int lcnt[3];
    __shared__ int base[3];
    __shared__ u16 tbank[32];
    __shared__ u16 trank[32];

    const int tid  = threadIdx.x;
    const int lane = tid & 63;
    const int wv   = tid >> 6;          // 0..7
    if (tid < 3) lcnt[tid] = 0;
    __syncthreads();

    const float* w0 = Wr;
    const float* w1 = Wr + D;
    const float* w2 = Wr + 2 * D;

    for (int t = 0; t < 4; ++t) {
        const int ltok = wv * 4 + t;
        const int tok  = tokbase + ltok;
        const float* x = X + (size_t)tok * D;
        u16* xb        = Xb + (size_t)tok * D;
        float a0 = 0.f, a1 = 0.f, a2 = 0.f;
        for (int d = lane * 4; d < D; d += 256) {
            float4 xv = *(const float4*)(x + d);
            uint2 pb = { pk2(xv.x, xv.y), pk2(xv.z, xv.w) };
            *(uint2*)(xb + d) = pb;                     // fused bf16 conversion
            float4 v0 = *(const float4*)(w0 + d);
            float4 v1 = *(const float4*)(w1 + d);
            float4 v2 = *(const float4*)(w2 + d);
            a0 += xv.x * v0.x + xv.y * v0.y + xv.z * v0.z + xv.w * v0.w;
            a1 += xv.x * v1.x + xv.y * v1.y + xv.z * v1.z + xv.w * v1.w;
            a2 += xv.x * v2.x + xv.y * v2.y + xv.z * v2.z + xv.w * v2.w;
        }
#pragma unroll
        for (int m = 32; m; m >>= 1) {
            a0 += __shfl_xor(a0, m);
            a1 += __shfl_xor(a1, m);
            a2 += __shfl_xor(a2, m);
        }
        if (lane == 0) {
            int s = 0; float best = a0;                 // strict >, first-max
            if (a1 > best) { best = a1; s = 1; }
            if (a2 > best) { best = a2; s = 2; }
            int r = atomicAdd(&lcnt[s], 1);             // LDS atomic
            tbank[ltok] = (u16)s;
            trank[ltok] = (u16)r;
        }
    }
    __syncthreads();

    if (tid < 3) base[tid] = atomicAdd(&cnt[tid * 32], lcnt[tid]);   // padded lines
    __syncthreads();

    if (tid < 32) {
        int s = tbank[tid];
        list[s * 8192 + base[s] + trank[tid]] = tokbase + tid;
    }
}

// ---------------------------------------------------------------------------
// Weight fp32 -> bf16 conversion. One thread = 8 elements (2 float4 -> uint4).
// Chunk ranges are compile-time: Wq 131072 | Wk 98304 | Wv 98304 |
// Wqb 393216 | Wkb 294912 -> 1015808 chunks = 3968 blocks of 256.
// ---------------------------------------------------------------------------
__global__ __launch_bounds__(256)
void cvt_weights(const float* __restrict__ Wq, const float* __restrict__ Wk,
                 const float* __restrict__ Wv, const float* __restrict__ Wqb,
                 const float* __restrict__ Wkb,
                 u16* __restrict__ WqB, u16* __restrict__ WkB, u16* __restrict__ WvB,
                 u16* __restrict__ WqbB, u16* __restrict__ WkbB)
{
    int g = blockIdx.x * 256 + threadIdx.x;
    const float* src; u16* dst; int e;
    if (g < 131072)      { src = Wq;  dst = WqB;  e = g; }
    else if (g < 229376) { src = Wk;  dst = WkB;  e = g - 131072; }
    else if (g < 327680) { src = Wv;  dst = WvB;  e = g - 229376; }
    else if (g < 720896) { src = Wqb; dst = WqbB; e = g - 327680; }
    else                 { src = Wkb; dst = WkbB; e = g - 720896; }
    float4 lo = *(const float4*)(src + (size_t)e * 8);
    float4 hi = *(const float4*)(src + (size_t)e * 8 + 4);
    uint4 p = { pk2(lo.x, lo.y), pk2(lo.z, lo.w), pk2(hi.x, hi.y), pk2(hi.z, hi.w) };
    *(uint4*)(dst + (size_t)e * 8) = p;
}

// ---------------------------------------------------------------------------
// GEMM core (bf16 in): 128x128 tile, BK=32, 4 waves 2x2, 4x4 MFMA 16x16x32.
// Staging: 4x global_load_lds width=16 per thread per K-step, DMA direct to
// LDS in linear chunk order (chunk c -> u16 offset 8c = row c>>2, koff
// (c&3)*8 -- identical layout to the fragment reads). Barriers on both sides
// of the compute phase (compiler drains vmcnt before s_barrier).
// ---------------------------------------------------------------------------
template <int KD>
DEVI void gemm_core(const u16* gA1, const u16* gA2, const u16* gB1, const u16* gB2,
                    u16* As, u16* Bs, int tid, int wv, int lane, f32x4 (&acc)[4][4])
{
    u16* dA1 = As + 8 * tid;
    u16* dA2 = As + 8 * tid + 2048;
    u16* dB1 = Bs + 8 * tid;
    u16* dB2 = Bs + 8 * tid + 2048;
    const int row15 = lane & 15;
    const int quad  = lane >> 4;
    const int wm = (wv & 1) * 64;
    const int wn = (wv >> 1) * 64;

    for (int k0 = 0; k0 < KD; k0 += 32) {
        gload16(gA1 + k0, dA1);
        gload16(gA2 + k0, dA2);
        gload16(gB1 + k0, dB1);
        gload16(gB2 + k0, dB2);
        __syncthreads();

        bf16x8 a[4], b[4];
#pragma unroll
        for (int i = 0; i < 4; ++i)
            a[i] = *(const bf16x8*)(As + (wm + i * 16 + row15) * 32 + quad * 8);
#pragma unroll
        for (int j = 0; j < 4; ++j)
            b[j] = *(const bf16x8*)(Bs + (wn + j * 16 + row15) * 32 + quad * 8);
#pragma unroll
        for (int i = 0; i < 4; ++i)
#pragma unroll
            for (int j = 0; j < 4; ++j)
                acc[i][j] = __builtin_amdgcn_mfma_f32_16x16x32_bf16(a[i], b[j], acc[i][j], 0, 0, 0);
        __syncthreads();
    }
}

// ---------------------------------------------------------------------------
// Plain GEMM: C[m,n] = sum_k A[m,k] * W[n,k], written to head layout (fp32).
// m = b*1024 + l ; n = h*64 + d ; out[((b*16+h)*1024 + l)*64 + d]
// ---------------------------------------------------------------------------
template <int KD>
__global__ __launch_bounds__(256)
void gemm_heads(const u16* __restrict__ A, const u16* __restrict__ W, float* __restrict__ out)
{
    __shared__ __align__(16) u16 As[128 * 32];
    __shared__ __align__(16) u16 Bs[128 * 32];
    const int tid  = threadIdx.x;
    const int lane = tid & 63;
    const int wv   = tid >> 6;
    const int rowbase = blockIdx.x * 128;
    const int nbase   = blockIdx.y * 128;
    const int r1   = tid >> 2;
    const int koff = (tid & 3) * 8;

    const u16* gA1 = A + (size_t)(rowbase + r1) * KD + koff;
    const u16* gA2 = A + (size_t)(rowbase + 64 + r1) * KD + koff;
    const u16* gB1 = W + (size_t)(nbase + r1) * KD + koff;
    const u16* gB2 = W + (size_t)(nbase + 64 + r1) * KD + koff;

    f32x4 acc[4][4];
#pragma unroll
    for (int i = 0; i < 4; ++i)
#pragma unroll
        for (int j = 0; j < 4; ++j)
            acc[i][j] = (f32x4){0.f, 0.f, 0.f, 0.f};

    gemm_core<KD>(gA1, gA2, gB1, gB2, As, Bs, tid, wv, lane, acc);

    const int row15 = lane & 15, quad = lane >> 4;
    const int wm = (wv & 1) * 64, wn = (wv >> 1) * 64;
#pragma unroll
    for (int i = 0; i < 4; ++i) {
#pragma unroll
        for (int r = 0; r < 4; ++r) {
            int m = rowbase + wm + i * 16 + quad * 4 + r;
            int bb = m >> 10, l = m & 1023;
#pragma unroll
            for (int j = 0; j < 4; ++j) {
                int n = nbase + wn + j * 16 + row15;
                size_t off = (((size_t)(bb * 16 + (n >> 6)) * 1024) + l) * 64 + (n & 63);
                out[off] = acc[i][j][r];
            }
        }
    }
}

// ---------------------------------------------------------------------------
// Row-gathered GEMM over per-bank token lists (Q'/K'). grid.x = 66 row-tiles
// shared across 3 banks (sum ceil(cnt_p/128) <= 66); grid.y = 8 col-tiles.
// Counters padded to 128-B lines: cnt[p*32].
// ---------------------------------------------------------------------------
template <int KD>
__global__ __launch_bounds__(256)
void gemm_prime(const u16* __restrict__ A, const u16* __restrict__ Wb,
                const int* __restrict__ cnt, const int* __restrict__ list,
                float* __restrict__ out)
{
    const int c0 = cnt[0], c1 = cnt[32], c2 = cnt[64];
    const int t0 = (c0 + 127) >> 7, t1 = (c1 + 127) >> 7, t2 = (c2 + 127) >> 7;
    const int rt = blockIdx.x;
    int bank, lt, cb;
    if (rt < t0)                { bank = 0; lt = rt;            cb = c0; }
    else if (rt < t0 + t1)      { bank = 1; lt = rt - t0;       cb = c1; }
    else if (rt < t0 + t1 + t2) { bank = 2; lt = rt - t0 - t1;  cb = c2; }
    else return;                       // uniform across block: no barrier reached

    const int* bl = list + bank * 8192;
    const u16* W = Wb + (size_t)bank * 1024 * KD;

    __shared__ __align__(16) u16 As[128 * 32];
    __shared__ __align__(16) u16 Bs[128 * 32];
    const int tid  = threadIdx.x;
    const int lane = tid & 63;
    const int wv   = tid >> 6;
    const int nbase = blockIdx.y * 128;
    const int r1   = tid >> 2;
    const int koff = (tid & 3) * 8;

    int i1 = lt * 128 + r1;       if (i1 >= cb) i1 = cb - 1;
    int i2 = lt * 128 + 64 + r1;  if (i2 >= cb) i2 = cb - 1;
    const u16* gA1 = A + (size_t)bl[i1] * KD + koff;
    const u16* gA2 = A + (size_t)bl[i2] * KD + koff;
    const u16* gB1 = W + (size_t)(nbase + r1) * KD + koff;
    const u16* gB2 = W + (size_t)(nbase + 64 + r1) * KD + koff;

    f32x4 acc[4][4];
#pragma unroll
    for (int i = 0; i < 4; ++i)
#pragma unroll
        for (int j = 0; j < 4; ++j)
            acc[i][j] = (f32x4){0.f, 0.f, 0.f, 0.f};

    gemm_core<KD>(gA1, gA2, gB1, gB2, As, Bs, tid, wv, lane, acc);

    const int row15 = lane & 15, quad = lane >> 4;
    const int wm = (wv & 1) * 64, wn = (wv >> 1) * 64;
#pragma unroll
    for (int i = 0; i < 4; ++i) {
#pragma unroll
        for (int r = 0; r < 4; ++r) {
            int idx = lt * 128 + wm + i * 16 + quad * 4 + r;
            if (idx < cb) {
                int m = bl[idx];
                int bb = m >> 10, l = m & 1023;
#pragma unroll
                for (int j = 0; j < 4; ++j) {
                    int n = nbase + wn + j * 16 + row15;
                    size_t off = (((size_t)(bb * 16 + (n >> 6)) * 1024) + l) * 64 + (n & 63);
                    out[off] = acc[i][j][r];
                }
            }
        }
    }
}

// ---------------------------------------------------------------------------
extern "C" void kernel_launch(void* const* d_in, const int* in_sizes, int n_in,
                              void* d_out, int out_size, void* d_ws, size_t ws_size,
                              hipStream_t stream)
{
    const float* img = (const float*)d_in[0];
    const float* txt = (const float*)d_in[1];
    const float* Wq  = (const float*)d_in[2];
    const float* Wk  = (const float*)d_in[3];
    const float* Wv  = (const float*)d_in[4];
    const float* Wqb = (const float*)d_in[5];
    const float* Wkb = (const float*)d_in[6];
    const float* Wrq = (const float*)d_in[7];
    const float* Wrk = (const float*)d_in[8];
    float* out = (float*)d_out;

    // ws layout: padded counters | q/k lists | bf16 copies (aligned at 256 KB)
    int* cntq  = (int*)d_ws;                    // ints [0],[32],[64]
    int* cntk  = (int*)d_ws + 128;
    int* qlist = (int*)d_ws + 256;              // 3*8192 ints
    int* klist = qlist + 3 * 8192;              // 3*8192 ints
    u16* imgB  = (u16*)((char*)d_ws + (1 << 18));
    u16* txtB  = imgB + (size_t)8192 * 1024;
    u16* WqB   = txtB + (size_t)8192 * 768;
    u16* WkB   = WqB  + (size_t)1024 * 1024;
    u16* WvB   = WkB  + (size_t)1024 * 768;
    u16* WqbB  = WvB  + (size_t)1024 * 768;
    u16* WkbB  = WqbB + (size_t)3 * 1024 * 1024;

    const size_t OSZ = (size_t)8 * 16 * 1024 * 64;   // 8,388,608 elements per output

    hipMemsetAsync(d_ws, 0, 1024, stream);   // zero padded counters (ws poisoned 0xAA)

    // routing + img/txt bf16 conversion (blocks [0,256)=img, [256,512)=txt)
    route_fused<<<512, 512, 0, stream>>>(img, Wrq, cntq, qlist, imgB,
                                         txt, Wrk, cntk, klist, txtB);
    cvt_weights<<<3968, 256, 0, stream>>>(Wq, Wk, Wv, Wqb, Wkb,
                                          WqB, WkB, WvB, WqbB, WkbB);

    gemm_heads<1024><<<dim3(64, 8), 256, 0, stream>>>(imgB, WqB, out);
    gemm_heads<768> <<<dim3(64, 8), 256, 0, stream>>>(txtB, WkB, out + OSZ);
    gemm_heads<768> <<<dim3(64, 8), 256, 0, stream>>>(txtB, WvB, out + 2 * OSZ);

    gemm_prime<1024><<<dim3(66, 8), 256, 0, stream>>>(imgB, WqbB, cntq, qlist, out + 3 * OSZ);
    gemm_prime<768> <<<dim3(66, 8), 256, 0, stream>>>(txtB, WkbB, cntk, klist, out + 4 * OSZ);
}

// Round 4
// 353.846 us; speedup vs baseline: 1.8418x; 1.1699x over previous
//
#include <hip/hip_runtime.h>

typedef unsigned short u16;
typedef unsigned int   u32;
typedef __bf16 bf16x8 __attribute__((ext_vector_type(8)));
typedef float  f32x4  __attribute__((ext_vector_type(4)));

#define DEVI __device__ __forceinline__

// B=8, S=N=1024, IMG_DIM=1024, TXT_DIM=768, INNER=1024, N_HEADS=16, HEAD_DIM=64, P=3
// Inputs: FLOAT32. Outputs: FLOAT32.
// out layout: Q | K | V | Q' | K', each [B,16,L,64] flat = 8*16*1024*64 elements
//
// Round-4 structure (post-mortem of r3: GEMMs stuck at ~200 TF because (1) each
// launch = 512 blocks = 2 blocks/CU grid-cap + 5 serialized launches, (2) 64-B
// LDS row stride -> ~8-way bank conflict on every ds_read_b128, (3) 2 barriers
// per 16 MFMA):
//   route_cvt : routing (proven r2 compaction) + img/txt bf16 conversion
//               + weight bf16 conversion, one launch.
//   gemm_all  : ALL 5 GEMMs in one 2592-block launch (roles by blockIdx range,
//               long-K first). BK=64 (half the barriers), XOR-swizzled LDS
//               (linear global_load_lds dest + pre-swizzled per-lane global
//               source + swizzled read -> 2-way conflict = free).
//               Same MFMA sequence as r3 -> bit-identical outputs.

DEVI u16 f2bf(float f) {
    u32 u = __float_as_uint(f);
    return (u16)((u + 0x7fffu + ((u >> 16) & 1u)) >> 16);   // RNE fp32->bf16
}
DEVI u32 pk2(float lo, float hi) { return (u32)f2bf(lo) | ((u32)f2bf(hi) << 16); }

DEVI void gload16(const u16* g, u16* s) {
    typedef __attribute__((address_space(1))) const unsigned int GU;
    typedef __attribute__((address_space(3))) unsigned int LU;
    __builtin_amdgcn_global_load_lds((GU*)g, (LU*)s, 16, 0, 0);  // 16B/lane DMA
}

// ---------------------------------------------------------------------------
// Fused routing + all fp32->bf16 conversion. 512 threads.
// blocks [0,256): img route (D=1024) | [256,512): txt route (D=768)
// blocks [512, 512+1984): weight conversion, 512 thr x 8 elem = 4096/block,
//   1984*512 = 1,015,808 chunks exactly (Wq 131072 | Wk 98304 | Wv 98304 |
//   Wqb 393216 | Wkb 294912).
// Routing: 32 tokens/block, 8 waves x 4 tokens, lane-strided float4 loads
// (stored as bf16 on the way), 64-lane butterfly, strict-> first argmax,
// LDS ranks + one global atomic per bank per block on padded 128-B lines.
// ---------------------------------------------------------------------------
__global__ __launch_bounds__(512)
void route_cvt(const float* __restrict__ img, const float* __restrict__ Wrq,
               int* __restrict__ cntq, int* __restrict__ qlist, u16* __restrict__ imgB,
               const float* __restrict__ txt, const float* __restrict__ Wrk,
               int* __restrict__ cntk, int* __restrict__ klist, u16* __restrict__ txtB,
               const float* __restrict__ Wq, const float* __restrict__ Wk,
               const float* __restrict__ Wv, const float* __restrict__ Wqb,
               const float* __restrict__ Wkb,
               u16* __restrict__ WqB, u16* __restrict__ WkB, u16* __restrict__ WvB,
               u16* __restrict__ WqbB, u16* __restrict__ WkbB)
{
    const int tid = threadIdx.x;

    if (blockIdx.x >= 512) {                    // ---- weight conversion part
        int g = (blockIdx.x - 512) * 512 + tid;
        const float* src; u16* dst; int e;
        if (g < 131072)      { src = Wq;  dst = WqB;  e = g; }
        else if (g < 229376) { src = Wk;  dst = WkB;  e = g - 131072; }
        else if (g < 327680) { src = Wv;  dst = WvB;  e = g - 229376; }
        else if (g < 720896) { src = Wqb; dst = WqbB; e = g - 327680; }
        else                 { src = Wkb; dst = WkbB; e = g - 720896; }
        float4 lo = *(const float4*)(src + (size_t)e * 8);
        float4 hi = *(const float4*)(src + (size_t)e * 8 + 4);
        uint4 p = { pk2(lo.x, lo.y), pk2(lo.z, lo.w), pk2(hi.x, hi.y), pk2(hi.z, hi.w) };
        *(uint4*)(dst + (size_t)e * 8) = p;
        return;
    }

    // ---- routing part (block-uniform branch; barriers only on this side)
    const float* X; const float* Wr; int D; int* cnt; int* list; u16* Xb; int tokbase;
    if (blockIdx.x < 256) { X = img; Wr = Wrq; D = 1024; cnt = cntq; list = qlist; Xb = imgB; tokbase = blockIdx.x * 32; }
    else                  { X = txt; Wr = Wrk; D = 768;  cnt = cntk; list = klist; Xb = txtB; tokbase = (blockIdx.x - 256) * 32; }

    __shared__ int lcnt[3];
    __shared__ int base[3];
    __shared__ u16 tbank[32];
    __shared__ u16 trank[32];

    const int lane = tid & 63;
    const int wv   = tid >> 6;          // 0..7
    if (tid < 3) lcnt[tid] = 0;
    __syncthreads();

    const float* w0 = Wr;
    const float* w1 = Wr + D;
    const float* w2 = Wr + 2 * D;

    for (int t = 0; t < 4; ++t) {
        const int ltok = wv * 4 + t;
        const int tok  = tokbase + ltok;
        const float* x = X + (size_t)tok * D;
        u16* xb        = Xb + (size_t)tok * D;
        float a0 = 0.f, a1 = 0.f, a2 = 0.f;
        for (int d = lane * 4; d < D; d += 256) {
            float4 xv = *(const float4*)(x + d);
            uint2 pb = { pk2(xv.x, xv.y), pk2(xv.z, xv.w) };
            *(uint2*)(xb + d) = pb;                     // fused bf16 conversion
            float4 v0 = *(const float4*)(w0 + d);
            float4 v1 = *(const float4*)(w1 + d);
            float4 v2 = *(const float4*)(w2 + d);
            a0 += xv.x * v0.x + xv.y * v0.y + xv.z * v0.z + xv.w * v0.w;
            a1 += xv.x * v1.x + xv.y * v1.y + xv.z * v1.z + xv.w * v1.w;
            a2 += xv.x * v2.x + xv.y * v2.y + xv.z * v2.z + xv.w * v2.w;
        }
#pragma unroll
        for (int m = 32; m; m >>= 1) {
            a0 += __shfl_xor(a0, m);
            a1 += __shfl_xor(a1, m);
            a2 += __shfl_xor(a2, m);
        }
        if (lane == 0) {
            int s = 0; float best = a0;                 // strict >, first-max
            if (a1 > best) { best = a1; s = 1; }
            if (a2 > best) { best = a2; s = 2; }
            int r = atomicAdd(&lcnt[s], 1);             // LDS atomic
            tbank[ltok] = (u16)s;
            trank[ltok] = (u16)r;
        }
    }
    __syncthreads();

    if (tid < 3) base[tid] = atomicAdd(&cnt[tid * 32], lcnt[tid]);   // padded lines
    __syncthreads();

    if (tid < 32) {
        int s = tbank[tid];
        list[s * 8192 + base[s] + trank[tid]] = tokbase + tid;
    }
}

// ---------------------------------------------------------------------------
// GEMM core, BK=64, XOR-swizzled LDS.
// Tile 128x128, 4 waves 2x2, each wave 4x4 MFMA 16x16x32 bf16, K in 64-steps
// (two 32-slices per barrier pair -> half the barriers of BK=32; identical
// ascending-K accumulation order = bit-identical results).
// Staging: 8x global_load_lds w=16 per thread per K-step, linear LDS dest
// (chunk c -> u16 offset 8c = row c>>3, slot c&7). The SOURCE k-slot is
// pre-swizzled: s_g = (c&7) ^ (row&7), so LDS[row][s] holds global slot
// s^(row&7). Fragment reads apply the same XOR -> lanes of a quad spread
// across all 8 16-B slots = 2 lanes/bank = conflict-free (G4, rule #21:
// linear dest + inverse-swizzled source + swizzled read).
// ---------------------------------------------------------------------------
template <int KD>
DEVI void gemm_core64(const u16* a0, const u16* a1, const u16* a2, const u16* a3,
                      const u16* b0, const u16* b1, const u16* b2, const u16* b3,
                      u16* As, u16* Bs, int tid, int wv, int lane, f32x4 (&acc)[4][4])
{
    u16* dA = As + 8 * tid;
    u16* dB = Bs + 8 * tid;
    const int row15 = lane & 15;
    const int quad  = lane >> 4;
    const int wm = (wv & 1) * 64;
    const int wn = (wv >> 1) * 64;

    for (int k0 = 0; k0 < KD; k0 += 64) {
        gload16(a0 + k0, dA);
        gload16(a1 + k0, dA + 2048);
        gload16(a2 + k0, dA + 4096);
        gload16(a3 + k0, dA + 6144);
        gload16(b0 + k0, dB);
        gload16(b1 + k0, dB + 2048);
        gload16(b2 + k0, dB + 4096);
        gload16(b3 + k0, dB + 6144);
        __syncthreads();

#pragma unroll
        for (int kk = 0; kk < 64; kk += 32) {
            bf16x8 a[4], b[4];
            const int sw = (kk >> 3) + quad;            // wanted global slot 0..7
#pragma unroll
            for (int i = 0; i < 4; ++i) {
                const int row = wm + i * 16 + row15;
                a[i] = *(const bf16x8*)(As + row * 64 + ((sw ^ (row & 7)) << 3));
            }
#pragma unroll
            for (int j = 0; j < 4; ++j) {
                const int row = wn + j * 16 + row15;
                b[j] = *(const bf16x8*)(Bs + row * 64 + ((sw ^ (row & 7)) << 3));
            }
#pragma unroll
            for (int i = 0; i < 4; ++i)
#pragma unroll
                for (int j = 0; j < 4; ++j)
                    acc[i][j] = __builtin_amdgcn_mfma_f32_16x16x32_bf16(a[i], b[j], acc[i][j], 0, 0, 0);
        }
        __syncthreads();
    }
}

DEVI void acc_init(f32x4 (&acc)[4][4]) {
#pragma unroll
    for (int i = 0; i < 4; ++i)
#pragma unroll
        for (int j = 0; j < 4; ++j)
            acc[i][j] = (f32x4){0.f, 0.f, 0.f, 0.f};
}

// ---------------------------------------------------------------------------
// Plain-GEMM body: C[m,n] = sum_k A[m,k]*W[n,k] -> head layout (fp32).
// lbid: rowtile = lbid>>3 (128 rows), ntile = lbid&7 (128 cols of INNER=1024).
// ---------------------------------------------------------------------------
template <int KD>
DEVI void gemm_heads_body(const u16* __restrict__ A, const u16* __restrict__ W,
                          float* __restrict__ out, int lbid, u16* As, u16* Bs)
{
    const int tid  = threadIdx.x;
    const int lane = tid & 63;
    const int wv   = tid >> 6;
    const int rowbase = (lbid >> 3) * 128;
    const int nbase   = (lbid & 7) * 128;
    const int r0 = tid >> 3;                             // 0..31
    const int sg = ((tid & 7) ^ (r0 & 7)) * 8;           // pre-swizzled k-slot (u16)

    const u16* gA0 = A + (size_t)(rowbase + r0)      * KD + sg;
    const u16* gA1 = A + (size_t)(rowbase + r0 + 32) * KD + sg;
    const u16* gA2 = A + (size_t)(rowbase + r0 + 64) * KD + sg;
    const u16* gA3 = A + (size_t)(rowbase + r0 + 96) * KD + sg;
    const u16* gB0 = W + (size_t)(nbase + r0)        * KD + sg;
    const u16* gB1 = W + (size_t)(nbase + r0 + 32)   * KD + sg;
    const u16* gB2 = W + (size_t)(nbase + r0 + 64)   * KD + sg;
    const u16* gB3 = W + (size_t)(nbase + r0 + 96)   * KD + sg;

    f32x4 acc[4][4];
    acc_init(acc);
    gemm_core64<KD>(gA0, gA1, gA2, gA3, gB0, gB1, gB2, gB3, As, Bs, tid, wv, lane, acc);

    const int row15 = lane & 15, quad = lane >> 4;
    const int wm = (wv & 1) * 64, wn = (wv >> 1) * 64;
#pragma unroll
    for (int i = 0; i < 4; ++i) {
#pragma unroll
        for (int r = 0; r < 4; ++r) {
            int m = rowbase + wm + i * 16 + quad * 4 + r;
            int bb = m >> 10, l = m & 1023;
#pragma unroll
            for (int j = 0; j < 4; ++j) {
                int n = nbase + wn + j * 16 + row15;
                size_t off = (((size_t)(bb * 16 + (n >> 6)) * 1024) + l) * 64 + (n & 63);
                out[off] = acc[i][j][r];
            }
        }
    }
}

// ---------------------------------------------------------------------------
// Row-gathered GEMM body (Q'/K'). lbid: rt = lbid>>3 in [0,66), ntile = lbid&7.
// Row tiles shared across 3 banks; counters on padded 128-B lines.
// ---------------------------------------------------------------------------
template <int KD>
DEVI void gemm_prime_body(const u16* __restrict__ A, const u16* __restrict__ Wb,
                          const int* __restrict__ cnt, const int* __restrict__ list,
                          float* __restrict__ out, int lbid, u16* As, u16* Bs)
{
    const int c0 = cnt[0], c1 = cnt[32], c2 = cnt[64];
    const int t0 = (c0 + 127) >> 7, t1 = (c1 + 127) >> 7, t2 = (c2 + 127) >> 7;
    const int rt = lbid >> 3;
    int bank, lt, cb;
    if (rt < t0)                { bank = 0; lt = rt;            cb = c0; }
    else if (rt < t0 + t1)      { bank = 1; lt = rt - t0;       cb = c1; }
    else if (rt < t0 + t1 + t2) { bank = 2; lt = rt - t0 - t1;  cb = c2; }
    else return;                       // block-uniform: no barrier reached

    const int* bl = list + bank * 8192;
    const u16* W = Wb + (size_t)bank * 1024 * KD;

    const int tid  = threadIdx.x;
    const int lane = tid & 63;
    const int wv   = tid >> 6;
    const int nbase = (lbid & 7) * 128;
    const int r0 = tid >> 3;
    const int sg = ((tid & 7) ^ (r0 & 7)) * 8;

    int i0 = lt * 128 + r0;       if (i0 >= cb) i0 = cb - 1;
    int i1 = lt * 128 + r0 + 32;  if (i1 >= cb) i1 = cb - 1;
    int i2 = lt * 128 + r0 + 64;  if (i2 >= cb) i2 = cb - 1;
    int i3 = lt * 128 + r0 + 96;  if (i3 >= cb) i3 = cb - 1;
    const u16* gA0 = A + (size_t)bl[i0] * KD + sg;
    const u16* gA1 = A + (size_t)bl[i1] * KD + sg;
    const u16* gA2 = A + (size_t)bl[i2] * KD + sg;
    const u16* gA3 = A + (size_t)bl[i3] * KD + sg;
    const u16* gB0 = W + (size_t)(nbase + r0)      * KD + sg;
    const u16* gB1 = W + (size_t)(nbase + r0 + 32) * KD + sg;
    const u16* gB2 = W + (size_t)(nbase + r0 + 64) * KD + sg;
    const u16* gB3 = W + (size_t)(nbase + r0 + 96) * KD + sg;

    f32x4 acc[4][4];
    acc_init(acc);
    gemm_core64<KD>(gA0, gA1, gA2, gA3, gB0, gB1, gB2, gB3, As, Bs, tid, wv, lane, acc);

    const int row15 = lane & 15, quad = lane >> 4;
    const int wm = (wv & 1) * 64, wn = (wv >> 1) * 64;
#pragma unroll
    for (int i = 0; i < 4; ++i) {
#pragma unroll
        for (int r = 0; r < 4; ++r) {
            int idx = lt * 128 + wm + i * 16 + quad * 4 + r;
            if (idx < cb) {
                int m = bl[idx];
                int bb = m >> 10, l = m & 1023;
#pragma unroll
                for (int j = 0; j < 4; ++j) {
                    int n = nbase + wn + j * 16 + row15;
                    size_t off = (((size_t)(bb * 16 + (n >> 6)) * 1024) + l) * 64 + (n & 63);
                    out[off] = acc[i][j][r];
                }
            }
        }
    }
}

// ---------------------------------------------------------------------------
// All 5 GEMMs in one launch: 2592 blocks, roles by range (block-uniform).
// Long-K paths first for tail packing:
// [0,528) Q' | [528,1040) Q | [1040,1568) K' | [1568,2080) K | [2080,2592) V
// ---------------------------------------------------------------------------
__global__ __launch_bounds__(256)
void gemm_all(const u16* __restrict__ imgB, const u16* __restrict__ txtB,
              const u16* __restrict__ WqB, const u16* __restrict__ WkB,
              const u16* __restrict__ WvB, const u16* __restrict__ WqbB,
              const u16* __restrict__ WkbB,
              const int* __restrict__ cntq, const int* __restrict__ qlist,
              const int* __restrict__ cntk, const int* __restrict__ klist,
              float* __restrict__ out)
{
    __shared__ __align__(16) u16 As[128 * 64];
    __shared__ __align__(16) u16 Bs[128 * 64];
    const size_t OSZ = (size_t)8 * 16 * 1024 * 64;
    const int bid = blockIdx.x;

    if (bid < 528)
        gemm_prime_body<1024>(imgB, WqbB, cntq, qlist, out + 3 * OSZ, bid, As, Bs);
    else if (bid < 1040)
        gemm_heads_body<1024>(imgB, WqB, out, bid - 528, As, Bs);
    else if (bid < 1568)
        gemm_prime_body<768>(txtB, WkbB, cntk, klist, out + 4 * OSZ, bid - 1040, As, Bs);
    else if (bid < 2080)
        gemm_heads_body<768>(txtB, WkB, out + OSZ, bid - 1568, As, Bs);
    else
        gemm_heads_body<768>(txtB, WvB, out + 2 * OSZ, bid - 2080, As, Bs);
}

// ---------------------------------------------------------------------------
extern "C" void kernel_launch(void* const* d_in, const int* in_sizes, int n_in,
                              void* d_out, int out_size, void* d_ws, size_t ws_size,
                              hipStream_t stream)
{
    const float* img = (const float*)d_in[0];
    const float* txt = (const float*)d_in[1];
    const float* Wq  = (const float*)d_in[2];
    const float* Wk  = (const float*)d_in[3];
    const float* Wv  = (const float*)d_in[4];
    const float* Wqb = (const float*)d_in[5];
    const float* Wkb = (const float*)d_in[6];
    const float* Wrq = (const float*)d_in[7];
    const float* Wrk = (const float*)d_in[8];
    float* out = (float*)d_out;

    // ws layout: padded counters | q/k lists | bf16 copies (at 256 KB)
    int* cntq  = (int*)d_ws;                    // ints [0],[32],[64]
    int* cntk  = (int*)d_ws + 128;
    int* qlist = (int*)d_ws + 256;              // 3*8192 ints
    int* klist = qlist + 3 * 8192;              // 3*8192 ints
    u16* imgB  = (u16*)((char*)d_ws + (1 << 18));
    u16* txtB  = imgB + (size_t)8192 * 1024;
    u16* WqB   = txtB + (size_t)8192 * 768;
    u16* WkB   = WqB  + (size_t)1024 * 1024;
    u16* WvB   = WkB  + (size_t)1024 * 768;
    u16* WqbB  = WvB  + (size_t)1024 * 768;
    u16* WkbB  = WqbB + (size_t)3 * 1024 * 1024;

    hipMemsetAsync(d_ws, 0, 1024, stream);   // zero padded counters (ws poisoned 0xAA)

    // routing + all bf16 conversion: 512 route blocks + 1984 cvt blocks
    route_cvt<<<2496, 512, 0, stream>>>(img, Wrq, cntq, qlist, imgB,
                                        txt, Wrk, cntk, klist, txtB,
                                        Wq, Wk, Wv, Wqb, Wkb,
                                        WqB, WkB, WvB, WqbB, WkbB);

    // all 5 GEMMs, one launch
    gemm_all<<<2592, 256, 0, stream>>>(imgB, txtB, WqB, WkB, WvB, WqbB, WkbB,
                                       cntq, qlist, cntk, klist, out);
}

// Round 5
// 348.961 us; speedup vs baseline: 1.8676x; 1.0140x over previous
//
#include <hip/hip_runtime.h>

typedef unsigned short u16;
typedef unsigned int   u32;
typedef __bf16 bf16x8 __attribute__((ext_vector_type(8)));
typedef float  f32x4  __attribute__((ext_vector_type(4)));

#define DEVI __device__ __forceinline__

// B=8, S=N=1024, IMG_DIM=1024, TXT_DIM=768, INNER=1024, N_HEADS=16, HEAD_DIM=64, P=3
// Inputs: FLOAT32. Outputs: FLOAT32.
// out layout: Q | K | V | Q' | K', each [B,16,L,64] flat = 8*16*1024*64 elements
//
// Round-5 (post-mortem r4: gemm_all memory-bound -- 467 MB HBM/dispatch vs
// 44 MB unique inputs; 73GF/467MB * 2.86TB/s == the measured 450 TF exactly):
//   + XCD-bijective block swizzle (2592 = 8*324): the 8 ntile-blocks sharing
//     an A rowtile now run consecutively on ONE XCD -> A-tile L2-resident.
//   + non-temporal C stores: the 165 MB fp32 output stream no longer evicts
//     A/W from L2/L3.
// Everything else (route_cvt, BK=64 XOR-swizzled core, MFMA order) unchanged
// -> bit-identical outputs.

DEVI u16 f2bf(float f) {
    u32 u = __float_as_uint(f);
    return (u16)((u + 0x7fffu + ((u >> 16) & 1u)) >> 16);   // RNE fp32->bf16
}
DEVI u32 pk2(float lo, float hi) { return (u32)f2bf(lo) | ((u32)f2bf(hi) << 16); }

DEVI void gload16(const u16* g, u16* s) {
    typedef __attribute__((address_space(1))) const unsigned int GU;
    typedef __attribute__((address_space(3))) unsigned int LU;
    __builtin_amdgcn_global_load_lds((GU*)g, (LU*)s, 16, 0, 0);  // 16B/lane DMA
}

// ---------------------------------------------------------------------------
// Fused routing + all fp32->bf16 conversion. 512 threads.
// blocks [0,256): img route (D=1024) | [256,512): txt route (D=768)
// blocks [512, 512+1984): weight conversion, 512 thr x 8 elem = 4096/block,
//   1984*512 = 1,015,808 chunks exactly (Wq 131072 | Wk 98304 | Wv 98304 |
//   Wqb 393216 | Wkb 294912).
// Routing: 32 tokens/block, 8 waves x 4 tokens, lane-strided float4 loads
// (stored as bf16 on the way), 64-lane butterfly, strict-> first argmax,
// LDS ranks + one global atomic per bank per block on padded 128-B lines.
// ---------------------------------------------------------------------------
__global__ __launch_bounds__(512)
void route_cvt(const float* __restrict__ img, const float* __restrict__ Wrq,
               int* __restrict__ cntq, int* __restrict__ qlist, u16* __restrict__ imgB,
               const float* __restrict__ txt, const float* __restrict__ Wrk,
               int* __restrict__ cntk, int* __restrict__ klist, u16* __restrict__ txtB,
               const float* __restrict__ Wq, const float* __restrict__ Wk,
               const float* __restrict__ Wv, const float* __restrict__ Wqb,
               const float* __restrict__ Wkb,
               u16* __restrict__ WqB, u16* __restrict__ WkB, u16* __restrict__ WvB,
               u16* __restrict__ WqbB, u16* __restrict__ WkbB)
{
    const int tid = threadIdx.x;

    if (blockIdx.x >= 512) {                    // ---- weight conversion part
        int g = (blockIdx.x - 512) * 512 + tid;
        const float* src; u16* dst; int e;
        if (g < 131072)      { src = Wq;  dst = WqB;  e = g; }
        else if (g < 229376) { src = Wk;  dst = WkB;  e = g - 131072; }
        else if (g < 327680) { src = Wv;  dst = WvB;  e = g - 229376; }
        else if (g < 720896) { src = Wqb; dst = WqbB; e = g - 327680; }
        else                 { src = Wkb; dst = WkbB; e = g - 720896; }
        float4 lo = *(const float4*)(src + (size_t)e * 8);
        float4 hi = *(const float4*)(src + (size_t)e * 8 + 4);
        uint4 p = { pk2(lo.x, lo.y), pk2(lo.z, lo.w), pk2(hi.x, hi.y), pk2(hi.z, hi.w) };
        *(uint4*)(dst + (size_t)e * 8) = p;
        return;
    }

    // ---- routing part (block-uniform branch; barriers only on this side)
    const float* X; const float* Wr; int D; int* cnt; int* list; u16* Xb; int tokbase;
    if (blockIdx.x < 256) { X = img; Wr = Wrq; D = 1024; cnt = cntq; list = qlist; Xb = imgB; tokbase = blockIdx.x * 32; }
    else                  { X = txt; Wr = Wrk; D = 768;  cnt = cntk; list = klist; Xb = txtB; tokbase = (blockIdx.x - 256) * 32; }

    __shared__ int lcnt[3];
    __shared__ int base[3];
    __shared__ u16 tbank[32];
    __shared__ u16 trank[32];

    const int lane = tid & 63;
    const int wv   = tid >> 6;          // 0..7
    if (tid < 3) lcnt[tid] = 0;
    __syncthreads();

    const float* w0 = Wr;
    const float* w1 = Wr + D;
    const float* w2 = Wr + 2 * D;

    for (int t = 0; t < 4; ++t) {
        const int ltok = wv * 4 + t;
        const int tok  = tokbase + ltok;
        const float* x = X + (size_t)tok * D;
        u16* xb        = Xb + (size_t)tok * D;
        float a0 = 0.f, a1 = 0.f, a2 = 0.f;
        for (int d = lane * 4; d < D; d += 256) {
            float4 xv = *(const float4*)(x + d);
            uint2 pb = { pk2(xv.x, xv.y), pk2(xv.z, xv.w) };
            *(uint2*)(xb + d) = pb;                     // fused bf16 conversion
            float4 v0 = *(const float4*)(w0 + d);
            float4 v1 = *(const float4*)(w1 + d);
            float4 v2 = *(const float4*)(w2 + d);
            a0 += xv.x * v0.x + xv.y * v0.y + xv.z * v0.z + xv.w * v0.w;
            a1 += xv.x * v1.x + xv.y * v1.y + xv.z * v1.z + xv.w * v1.w;
            a2 += xv.x * v2.x + xv.y * v2.y + xv.z * v2.z + xv.w * v2.w;
        }
#pragma unroll
        for (int m = 32; m; m >>= 1) {
            a0 += __shfl_xor(a0, m);
            a1 += __shfl_xor(a1, m);
            a2 += __shfl_xor(a2, m);
        }
        if (lane == 0) {
            int s = 0; float best = a0;                 // strict >, first-max
            if (a1 > best) { best = a1; s = 1; }
            if (a2 > best) { best = a2; s = 2; }
            int r = atomicAdd(&lcnt[s], 1);             // LDS atomic
            tbank[ltok] = (u16)s;
            trank[ltok] = (u16)r;
        }
    }
    __syncthreads();

    if (tid < 3) base[tid] = atomicAdd(&cnt[tid * 32], lcnt[tid]);   // padded lines
    __syncthreads();

    if (tid < 32) {
        int s = tbank[tid];
        list[s * 8192 + base[s] + trank[tid]] = tokbase + tid;
    }
}

// ---------------------------------------------------------------------------
// GEMM core, BK=64, XOR-swizzled LDS (proven r4: bank conflicts = 0).
// Tile 128x128, 4 waves 2x2, each wave 4x4 MFMA 16x16x32 bf16, K in 64-steps.
// Staging: 8x global_load_lds w=16 per thread per K-step, linear LDS dest,
// pre-swizzled global source slot, same XOR on the fragment read.
// ---------------------------------------------------------------------------
template <int KD>
DEVI void gemm_core64(const u16* a0, const u16* a1, const u16* a2, const u16* a3,
                      const u16* b0, const u16* b1, const u16* b2, const u16* b3,
                      u16* As, u16* Bs, int tid, int wv, int lane, f32x4 (&acc)[4][4])
{
    u16* dA = As + 8 * tid;
    u16* dB = Bs + 8 * tid;
    const int row15 = lane & 15;
    const int quad  = lane >> 4;
    const int wm = (wv & 1) * 64;
    const int wn = (wv >> 1) * 64;

    for (int k0 = 0; k0 < KD; k0 += 64) {
        gload16(a0 + k0, dA);
        gload16(a1 + k0, dA + 2048);
        gload16(a2 + k0, dA + 4096);
        gload16(a3 + k0, dA + 6144);
        gload16(b0 + k0, dB);
        gload16(b1 + k0, dB + 2048);
        gload16(b2 + k0, dB + 4096);
        gload16(b3 + k0, dB + 6144);
        __syncthreads();

#pragma unroll
        for (int kk = 0; kk < 64; kk += 32) {
            bf16x8 a[4], b[4];
            const int sw = (kk >> 3) + quad;            // wanted global slot 0..7
#pragma unroll
            for (int i = 0; i < 4; ++i) {
                const int row = wm + i * 16 + row15;
                a[i] = *(const bf16x8*)(As + row * 64 + ((sw ^ (row & 7)) << 3));
            }
#pragma unroll
            for (int j = 0; j < 4; ++j) {
                const int row = wn + j * 16 + row15;
                b[j] = *(const bf16x8*)(Bs + row * 64 + ((sw ^ (row & 7)) << 3));
            }
#pragma unroll
            for (int i = 0; i < 4; ++i)
#pragma unroll
                for (int j = 0; j < 4; ++j)
                    acc[i][j] = __builtin_amdgcn_mfma_f32_16x16x32_bf16(a[i], b[j], acc[i][j], 0, 0, 0);
        }
        __syncthreads();
    }
}

DEVI void acc_init(f32x4 (&acc)[4][4]) {
#pragma unroll
    for (int i = 0; i < 4; ++i)
#pragma unroll
        for (int j = 0; j < 4; ++j)
            acc[i][j] = (f32x4){0.f, 0.f, 0.f, 0.f};
}

// ---------------------------------------------------------------------------
// Plain-GEMM body: C[m,n] = sum_k A[m,k]*W[n,k] -> head layout (fp32).
// lbid: rowtile = lbid>>3 (128 rows), ntile = lbid&7 (128 cols of INNER=1024).
// C-writes are non-temporal (outputs never re-read; keep L2/L3 for A/W).
// ---------------------------------------------------------------------------
template <int KD>
DEVI void gemm_heads_body(const u16* __restrict__ A, const u16* __restrict__ W,
                          float* __restrict__ out, int lbid, u16* As, u16* Bs)
{
    const int tid  = threadIdx.x;
    const int lane = tid & 63;
    const int wv   = tid >> 6;
    const int rowbase = (lbid >> 3) * 128;
    const int nbase   = (lbid & 7) * 128;
    const int r0 = tid >> 3;                             // 0..31
    const int sg = ((tid & 7) ^ (r0 & 7)) * 8;           // pre-swizzled k-slot (u16)

    const u16* gA0 = A + (size_t)(rowbase + r0)      * KD + sg;
    const u16* gA1 = A + (size_t)(rowbase + r0 + 32) * KD + sg;
    const u16* gA2 = A + (size_t)(rowbase + r0 + 64) * KD + sg;
    const u16* gA3 = A + (size_t)(rowbase + r0 + 96) * KD + sg;
    const u16* gB0 = W + (size_t)(nbase + r0)        * KD + sg;
    const u16* gB1 = W + (size_t)(nbase + r0 + 32)   * KD + sg;
    const u16* gB2 = W + (size_t)(nbase + r0 + 64)   * KD + sg;
    const u16* gB3 = W + (size_t)(nbase + r0 + 96)   * KD + sg;

    f32x4 acc[4][4];
    acc_init(acc);
    gemm_core64<KD>(gA0, gA1, gA2, gA3, gB0, gB1, gB2, gB3, As, Bs, tid, wv, lane, acc);

    const int row15 = lane & 15, quad = lane >> 4;
    const int wm = (wv & 1) * 64, wn = (wv >> 1) * 64;
#pragma unroll
    for (int i = 0; i < 4; ++i) {
#pragma unroll
        for (int r = 0; r < 4; ++r) {
            int m = rowbase + wm + i * 16 + quad * 4 + r;
            int bb = m >> 10, l = m & 1023;
#pragma unroll
            for (int j = 0; j < 4; ++j) {
                int n = nbase + wn + j * 16 + row15;
                size_t off = (((size_t)(bb * 16 + (n >> 6)) * 1024) + l) * 64 + (n & 63);
                __builtin_nontemporal_store(acc[i][j][r], &out[off]);
            }
        }
    }
}

// ---------------------------------------------------------------------------
// Row-gathered GEMM body (Q'/K'). lbid: rt = lbid>>3 in [0,66), ntile = lbid&7.
// Row tiles shared across 3 banks; counters on padded 128-B lines.
// ---------------------------------------------------------------------------
template <int KD>
DEVI void gemm_prime_body(const u16* __restrict__ A, const u16* __restrict__ Wb,
                          const int* __restrict__ cnt, const int* __restrict__ list,
                          float* __restrict__ out, int lbid, u16* As, u16* Bs)
{
    const int c0 = cnt[0], c1 = cnt[32], c2 = cnt[64];
    const int t0 = (c0 + 127) >> 7, t1 = (c1 + 127) >> 7, t2 = (c2 + 127) >> 7;
    const int rt = lbid >> 3;
    int bank, lt, cb;
    if (rt < t0)                { bank = 0; lt = rt;            cb = c0; }
    else if (rt < t0 + t1)      { bank = 1; lt = rt - t0;       cb = c1; }
    else if (rt < t0 + t1 + t2) { bank = 2; lt = rt - t0 - t1;  cb = c2; }
    else return;                       // block-uniform: no barrier reached

    const int* bl = list + bank * 8192;
    const u16* W = Wb + (size_t)bank * 1024 * KD;

    const int tid  = threadIdx.x;
    const int lane = tid & 63;
    const int wv   = tid >> 6;
    const int nbase = (lbid & 7) * 128;
    const int r0 = tid >> 3;
    const int sg = ((tid & 7) ^ (r0 & 7)) * 8;

    int i0 = lt * 128 + r0;       if (i0 >= cb) i0 = cb - 1;
    int i1 = lt * 128 + r0 + 32;  if (i1 >= cb) i1 = cb - 1;
    int i2 = lt * 128 + r0 + 64;  if (i2 >= cb) i2 = cb - 1;
    int i3 = lt * 128 + r0 + 96;  if (i3 >= cb) i3 = cb - 1;
    const u16* gA0 = A + (size_t)bl[i0] * KD + sg;
    const u16* gA1 = A + (size_t)bl[i1] * KD + sg;
    const u16* gA2 = A + (size_t)bl[i2] * KD + sg;
    const u16* gA3 = A + (size_t)bl[i3] * KD + sg;
    const u16* gB0 = W + (size_t)(nbase + r0)      * KD + sg;
    const u16* gB1 = W + (size_t)(nbase + r0 + 32) * KD + sg;
    const u16* gB2 = W + (size_t)(nbase + r0 + 64) * KD + sg;
    const u16* gB3 = W + (size_t)(nbase + r0 + 96) * KD + sg;

    f32x4 acc[4][4];
    acc_init(acc);
    gemm_core64<KD>(gA0, gA1, gA2, gA3, gB0, gB1, gB2, gB3, As, Bs, tid, wv, lane, acc);

    const int row15 = lane & 15, quad = lane >> 4;
    const int wm = (wv & 1) * 64, wn = (wv >> 1) * 64;
#pragma unroll
    for (int i = 0; i < 4; ++i) {
#pragma unroll
        for (int r = 0; r < 4; ++r) {
            int idx = lt * 128 + wm + i * 16 + quad * 4 + r;
            if (idx < cb) {
                int m = bl[idx];
                int bb = m >> 10, l = m & 1023;
#pragma unroll
                for (int j = 0; j < 4; ++j) {
                    int n = nbase + wn + j * 16 + row15;
                    size_t off = (((size_t)(bb * 16 + (n >> 6)) * 1024) + l) * 64 + (n & 63);
                    __builtin_nontemporal_store(acc[i][j][r], &out[off]);
                }
            }
        }
    }
}

// ---------------------------------------------------------------------------
// All 5 GEMMs in one launch: 2592 blocks, roles by range (block-uniform).
// XCD-bijective swizzle: 2592 = 8*324 exactly, swz = (bid%8)*324 + bid/8.
// Blocks sharing an A rowtile (8 consecutive work-ids) now execute on the
// SAME XCD back-to-back -> A-tile stays in that XCD's L2 (r4: each of the 8
// XCDs fetched it separately -> 291 MB HBM fetch vs 44 MB unique input).
// [0,528) Q' | [528,1040) Q | [1040,1568) K' | [1568,2080) K | [2080,2592) V
// ---------------------------------------------------------------------------
__global__ __launch_bounds__(256)
void gemm_all(const u16* __restrict__ imgB, const u16* __restrict__ txtB,
              const u16* __restrict__ WqB, const u16* __restrict__ WkB,
              const u16* __restrict__ WvB, const u16* __restrict__ WqbB,
              const u16* __restrict__ WkbB,
              const int* __restrict__ cntq, const int* __restrict__ qlist,
              const int* __restrict__ cntk, const int* __restrict__ klist,
              float* __restrict__ out)
{
    __shared__ __align__(16) u16 As[128 * 64];
    __shared__ __align__(16) u16 Bs[128 * 64];
    const size_t OSZ = (size_t)8 * 16 * 1024 * 64;
    const int bid = (blockIdx.x & 7) * 324 + (blockIdx.x >> 3);   // XCD swizzle

    if (bid < 528)
        gemm_prime_body<1024>(imgB, WqbB, cntq, qlist, out + 3 * OSZ, bid, As, Bs);
    else if (bid < 1040)
        gemm_heads_body<1024>(imgB, WqB, out, bid - 528, As, Bs);
    else if (bid < 1568)
        gemm_prime_body<768>(txtB, WkbB, cntk, klist, out + 4 * OSZ, bid - 1040, As, Bs);
    else if (bid < 2080)
        gemm_heads_body<768>(txtB, WkB, out + OSZ, bid - 1568, As, Bs);
    else
        gemm_heads_body<768>(txtB, WvB, out + 2 * OSZ, bid - 2080, As, Bs);
}

// ---------------------------------------------------------------------------
extern "C" void kernel_launch(void* const* d_in, const int* in_sizes, int n_in,
                              void* d_out, int out_size, void* d_ws, size_t ws_size,
                              hipStream_t stream)
{
    const float* img = (const float*)d_in[0];
    const float* txt = (const float*)d_in[1];
    const float* Wq  = (const float*)d_in[2];
    const float* Wk  = (const float*)d_in[3];
    const float* Wv  = (const float*)d_in[4];
    const float* Wqb = (const float*)d_in[5];
    const float* Wkb = (const float*)d_in[6];
    const float* Wrq = (const float*)d_in[7];
    const float* Wrk = (const float*)d_in[8];
    float* out = (float*)d_out;

    // ws layout: padded counters | q/k lists | bf16 copies (at 256 KB)
    int* cntq  = (int*)d_ws;                    // ints [0],[32],[64]
    int* cntk  = (int*)d_ws + 128;
    int* qlist = (int*)d_ws + 256;              // 3*8192 ints
    int* klist = qlist + 3 * 8192;              // 3*8192 ints
    u16* imgB  = (u16*)((char*)d_ws + (1 << 18));
    u16* txtB  = imgB + (size_t)8192 * 1024;
    u16* WqB   = txtB + (size_t)8192 * 768;
    u16* WkB   = WqB  + (size_t)1024 * 1024;
    u16* WvB   = WkB  + (size_t)1024 * 768;
    u16* WqbB  = WvB  + (size_t)1024 * 768;
    u16* WkbB  = WqbB + (size_t)3 * 1024 * 1024;

    hipMemsetAsync(d_ws, 0, 1024, stream);   // zero padded counters (ws poisoned 0xAA)

    // routing + all bf16 conversion: 512 route blocks + 1984 cvt blocks
    route_cvt<<<2496, 512, 0, stream>>>(img, Wrq, cntq, qlist, imgB,
                                        txt, Wrk, cntk, klist, txtB,
                                        Wq, Wk, Wv, Wqb, Wkb,
                                        WqB, WkB, WvB, WqbB, WkbB);

    // all 5 GEMMs, one launch (XCD-swizzled inside)
    gemm_all<<<2592, 256, 0, stream>>>(imgB, txtB, WqB, WkB, WvB, WqbB, WkbB,
                                       cntq, qlist, cntk, klist, out);
}